// Round 1
// baseline (212.319 us; speedup 1.0000x reference)
//
#include <hip/hip_runtime.h>
#include <math.h>

#define NPG  128   // nodes per graph
#define HID  128
#define KSEL 64
#define NT   256

// One block per graph. LDS: Hs (x -> H0 -> h) 64KB + As (dense normalized adj) 64KB.
__global__ __launch_bounds__(NT) void sagpool_fused(
    const float* __restrict__ x,
    const int*   __restrict__ esrc,
    const int*   __restrict__ edst,
    const float* __restrict__ W1,
    const float* __restrict__ b1,
    const float* __restrict__ Ws,
    const float* __restrict__ bsp,
    const float* __restrict__ Wlin,
    const float* __restrict__ blin,
    float* __restrict__ out,
    int epg)
{
    __shared__ float Hs[NPG][HID];   // 64 KB: x tile, then H0, then h
    __shared__ float As[NPG][NPG];   // 64 KB: dense normalized adjacency
    __shared__ float rsl[NPG];
    __shared__ int   degl[NPG];
    __shared__ float spl[NPG];       // h @ Ws
    __shared__ float scl[NPG];       // scores
    __shared__ float wgt[NPG];       // tanh(score)/K for kept nodes, else 0
    __shared__ float pooled[HID];

    const int g = blockIdx.x;
    const int t = threadIdx.x;
    const int node0 = g * NPG;
    const long e0 = (long)g * epg;

    if (t < NPG) degl[t] = 1;  // self loop

    // zero A, stage x tile (coalesced float4)
    {
        float4* Af = reinterpret_cast<float4*>(&As[0][0]);
        float4* Hf = reinterpret_cast<float4*>(&Hs[0][0]);
        const float4* xg = reinterpret_cast<const float4*>(x + (long)node0 * HID);
        const float4 z = make_float4(0.f, 0.f, 0.f, 0.f);
        for (int i = t; i < NPG * HID / 4; i += NT) {
            Af[i] = z;
            Hf[i] = xg[i];
        }
    }
    __syncthreads();

    // degree (in-degree on dst, + self loop)
    for (int e = t; e < epg; e += NT) {
        int d = edst[e0 + e] - node0;
        atomicAdd(&degl[d], 1);
    }
    __syncthreads();
    if (t < NPG) rsl[t] = 1.0f / sqrtf((float)degl[t]);
    __syncthreads();

    // A[d][s] += rs[s]*rs[d] per edge (multi-edges accumulate, matching segment_sum)
    for (int e = t; e < epg; e += NT) {
        int s = esrc[e0 + e] - node0;
        int d = edst[e0 + e] - node0;
        atomicAdd(&As[d][s], rsl[s] * rsl[d]);
    }
    __syncthreads();
    if (t < NPG) As[t][t] += rsl[t] * rsl[t];   // self loop: 1/deg

    // ---- GEMM1: H0 = x @ W1 (x in Hs; W1 from global, L2-hot) ----
    // thread -> 4 columns {c0,c0+32,c0+64,c0+96}, 16 rows [q*16, q*16+16)
    const int c0 = t & 31;
    const int q  = t >> 5;
    const int r0 = q * 16;

    float acc[16][4];
    #pragma unroll
    for (int rr = 0; rr < 16; ++rr)
        #pragma unroll
        for (int cc = 0; cc < 4; ++cc) acc[rr][cc] = 0.f;

    for (int k0 = 0; k0 < HID; k0 += 4) {
        float w[4][4];
        #pragma unroll
        for (int j = 0; j < 4; ++j)
            #pragma unroll
            for (int cc = 0; cc < 4; ++cc)
                w[j][cc] = W1[(k0 + j) * HID + c0 + cc * 32];
        #pragma unroll
        for (int rr = 0; rr < 16; ++rr) {
            float4 xv = *reinterpret_cast<const float4*>(&Hs[r0 + rr][k0]);
            #pragma unroll
            for (int cc = 0; cc < 4; ++cc)
                acc[rr][cc] += xv.x * w[0][cc] + xv.y * w[1][cc]
                             + xv.z * w[2][cc] + xv.w * w[3][cc];
        }
    }
    __syncthreads();   // all reads of Hs(=x) complete
    #pragma unroll
    for (int rr = 0; rr < 16; ++rr)
        #pragma unroll
        for (int cc = 0; cc < 4; ++cc)
            Hs[r0 + rr][c0 + cc * 32] = acc[rr][cc];
    __syncthreads();   // Hs = H0; As fully built

    // ---- agg = A @ H0 ----
    #pragma unroll
    for (int rr = 0; rr < 16; ++rr)
        #pragma unroll
        for (int cc = 0; cc < 4; ++cc) acc[rr][cc] = 0.f;

    for (int k0 = 0; k0 < NPG; k0 += 4) {
        float hv[4][4];
        #pragma unroll
        for (int j = 0; j < 4; ++j)
            #pragma unroll
            for (int cc = 0; cc < 4; ++cc)
                hv[j][cc] = Hs[k0 + j][c0 + cc * 32];
        #pragma unroll
        for (int rr = 0; rr < 16; ++rr) {
            float4 av = *reinterpret_cast<const float4*>(&As[r0 + rr][k0]);
            #pragma unroll
            for (int cc = 0; cc < 4; ++cc)
                acc[rr][cc] += av.x * hv[0][cc] + av.y * hv[1][cc]
                             + av.z * hv[2][cc] + av.w * hv[3][cc];
        }
    }
    __syncthreads();   // all reads of Hs(=H0) complete

    // h = relu(agg + b1) -> Hs
    {
        float bb[4];
        #pragma unroll
        for (int cc = 0; cc < 4; ++cc) bb[cc] = b1[c0 + cc * 32];
        #pragma unroll
        for (int rr = 0; rr < 16; ++rr)
            #pragma unroll
            for (int cc = 0; cc < 4; ++cc)
                Hs[r0 + rr][c0 + cc * 32] = fmaxf(acc[rr][cc] + bb[cc], 0.f);
    }
    __syncthreads();

    // score_pre = h @ Ws  (one node per thread, first 128 threads)
    if (t < NPG) {
        const float4* Wsf = reinterpret_cast<const float4*>(Ws);
        float s = 0.f;
        #pragma unroll 4
        for (int k = 0; k < HID / 4; ++k) {
            float4 hv = *reinterpret_cast<const float4*>(&Hs[t][k * 4]);
            float4 wv = Wsf[k];
            s += hv.x * wv.x + hv.y * wv.y + hv.z * wv.z + hv.w * wv.w;
        }
        spl[t] = s;
    }
    __syncthreads();

    // score = A @ score_pre + bs
    if (t < NPG) {
        float s = 0.f;
        #pragma unroll 4
        for (int k = 0; k < NPG / 4; ++k) {
            float4 av = *reinterpret_cast<const float4*>(&As[t][k * 4]);
            float4 pv = *reinterpret_cast<const float4*>(&spl[k * 4]);
            s += av.x * pv.x + av.y * pv.y + av.z * pv.z + av.w * pv.w;
        }
        scl[t] = s + bsp[0];
    }
    __syncthreads();

    // top-K by exact rank (jax.lax.top_k tie-break: lower index first).
    // mean over kept nodes is order-invariant -> only need membership + weight.
    if (t < NPG) {
        float v = scl[t];
        int rank = 0;
        for (int j = 0; j < NPG; ++j) {
            float u = scl[j];
            rank += (u > v || (u == v && j < t)) ? 1 : 0;
        }
        wgt[t] = (rank < KSEL) ? tanhf(v) * (1.0f / KSEL) : 0.f;
    }
    __syncthreads();

    // pooled[c] = sum_r wgt[r] * h[r][c]
    if (t < NPG) {
        float p = 0.f;
        for (int r = 0; r < NPG; ++r)
            p += wgt[r] * Hs[r][t];
        pooled[t] = p;
    }
    __syncthreads();

    // out[g] = pooled @ Wlin + blin
    if (t < NPG) {
        float o = blin[t];
        #pragma unroll 4
        for (int k = 0; k < HID; ++k)
            o += pooled[k] * Wlin[k * HID + t];
        out[(long)g * HID + t] = o;
    }
}

extern "C" void kernel_launch(void* const* d_in, const int* in_sizes, int n_in,
                              void* d_out, int out_size, void* d_ws, size_t ws_size,
                              hipStream_t stream) {
    const float* x    = (const float*)d_in[0];
    const int*   ei   = (const int*)  d_in[1];
    const float* W1   = (const float*)d_in[3];
    const float* b1   = (const float*)d_in[4];
    const float* Ws   = (const float*)d_in[5];
    const float* bs   = (const float*)d_in[6];
    const float* Wlin = (const float*)d_in[7];
    const float* blin = (const float*)d_in[8];
    float* out = (float*)d_out;

    const int E = in_sizes[1] / 2;          // 1048576
    const int nnodes = in_sizes[0] / HID;   // 65536
    const int B = nnodes / NPG;             // 512
    const int epg = E / B;                  // 2048

    sagpool_fused<<<B, NT, 0, stream>>>(x, ei, ei + E, W1, b1, Ws, bs,
                                        Wlin, blin, out, epg);
}

// Round 2
// 139.597 us; speedup vs baseline: 1.5209x; 1.5209x over previous
//
#include <hip/hip_runtime.h>
#include <math.h>

#define NPG  128
#define HID  128
#define KSEL 64
#define NT   256
#define CSRCAP 2432   // 2048 edges + up to 128*3 pad (per-node counts padded to x4)

#define FMA4(A,S,W) { (A).x += (S)*(W).x; (A).y += (S)*(W).y; (A).z += (S)*(W).z; (A).w += (S)*(W).w; }

__global__ __launch_bounds__(NT, 2) void sagpool_fused(
    const float* __restrict__ x,
    const int*   __restrict__ esrc,
    const int*   __restrict__ edst,
    const float* __restrict__ W1,
    const float* __restrict__ b1,
    const float* __restrict__ Ws,
    const float* __restrict__ bsp,
    const float* __restrict__ Wlin,
    const float* __restrict__ blin,
    float* __restrict__ out,
    int epg)
{
    // ~72 KB LDS -> 2 blocks/CU
    __shared__ float Hs[NPG + 1][HID];          // H0' (rs-scaled) then h; row 128 = zero dummy
    __shared__ unsigned char srcs[CSRCAP];      // CSR src indices (uchar), pad entries = 128
    __shared__ int   degl[NPG];
    __shared__ int   off[NPG + 1];              // padded CSR offsets (multiples of 4)
    __shared__ int   cur[NPG];
    __shared__ float rsl[NPG];
    __shared__ float spl[NPG + 1];              // rs-scaled h@Ws; spl[128] = 0
    __shared__ float scl[NPG];
    __shared__ float wgt[NPG];
    __shared__ float pooled[HID];
    __shared__ float pp[2 * HID];
    __shared__ int   wsum[2];

    const int g = blockIdx.x, t = threadIdx.x;
    const int node0 = g * NPG;
    const long e0 = (long)g * epg;
    const int lane = t & 63, wv = t >> 6;

    // ---- load this graph's edges into registers (single global pass) ----
    int es[8], ed[8];
#pragma unroll
    for (int i = 0; i < 8; ++i) {
        int e = i * NT + t;
        es[i] = esrc[e0 + e] - node0;
        ed[i] = edst[e0 + e] - node0;
    }
    if (t < NPG) degl[t] = 0;
    if (t < HID) Hs[NPG][t] = 0.f;                       // dummy row for CSR padding
    for (int i = t; i < CSRCAP / 4; i += NT)
        reinterpret_cast<int*>(srcs)[i] = (int)0x80808080;  // fill with 128
    __syncthreads();

#pragma unroll
    for (int i = 0; i < 8; ++i) atomicAdd(&degl[ed[i]], 1);
    __syncthreads();

    // ---- rsqrt(deg+1) + exclusive scan of padded counts (wave shfl scan) ----
    int pc = 0;
    if (t < NPG) {
        int dg = degl[t];
        rsl[t] = rsqrtf((float)(dg + 1));
        pc = (dg + 3) & ~3;
    }
    int vscan = pc;
#pragma unroll
    for (int d = 1; d < 64; d <<= 1) {
        int u = __shfl_up(vscan, (unsigned)d, 64);
        if (lane >= d) vscan += u;
    }
    if (t < NPG && lane == 63) wsum[wv] = vscan;
    __syncthreads();
    if (t < NPG) {
        int inc = vscan + ((wv == 1) ? wsum[0] : 0);
        int ex = inc - pc;
        off[t] = ex; cur[t] = ex;
        if (t == NPG - 1) off[NPG] = inc;
    }
    __syncthreads();

    // ---- scatter edges into CSR (uchar local src idx) ----
#pragma unroll
    for (int i = 0; i < 8; ++i) {
        int slot = atomicAdd(&cur[ed[i]], 1);
        srcs[slot] = (unsigned char)es[i];
    }

    // ---- GEMM1: H0 = x @ W1, store rs-scaled into Hs. x, W1 from global (L1). ----
    // thread -> 8 rows [q*8, q*8+8), 8 cols [c0*8, c0*8+8)
    {
        const int c0 = t & 15, q = t >> 4;
        const int r0b = q * 8, cb = c0 * 8;
        float4 acc0[8], acc1[8];
#pragma unroll
        for (int r = 0; r < 8; ++r) {
            acc0[r] = make_float4(0.f, 0.f, 0.f, 0.f);
            acc1[r] = make_float4(0.f, 0.f, 0.f, 0.f);
        }
        const float* xg = x + (long)node0 * HID;
        for (int k0 = 0; k0 < HID; k0 += 4) {
            float4 w0[4], w1[4];
#pragma unroll
            for (int j = 0; j < 4; ++j) {
                w0[j] = *reinterpret_cast<const float4*>(&W1[(k0 + j) * HID + cb]);
                w1[j] = *reinterpret_cast<const float4*>(&W1[(k0 + j) * HID + cb + 4]);
            }
#pragma unroll
            for (int r = 0; r < 8; ++r) {
                float4 xv = *reinterpret_cast<const float4*>(&xg[(r0b + r) * HID + k0]);
                FMA4(acc0[r], xv.x, w0[0]); FMA4(acc1[r], xv.x, w1[0]);
                FMA4(acc0[r], xv.y, w0[1]); FMA4(acc1[r], xv.y, w1[1]);
                FMA4(acc0[r], xv.z, w0[2]); FMA4(acc1[r], xv.z, w1[2]);
                FMA4(acc0[r], xv.w, w0[3]); FMA4(acc1[r], xv.w, w1[3]);
            }
        }
#pragma unroll
        for (int r = 0; r < 8; ++r) {
            float sc = rsl[r0b + r];
            float4 v0 = acc0[r], v1 = acc1[r];
            v0.x *= sc; v0.y *= sc; v0.z *= sc; v0.w *= sc;
            v1.x *= sc; v1.y *= sc; v1.z *= sc; v1.w *= sc;
            *reinterpret_cast<float4*>(&Hs[r0b + r][cb])     = v0;
            *reinterpret_cast<float4*>(&Hs[r0b + r][cb + 4]) = v1;
        }
    }
    __syncthreads();   // H0' complete, CSR complete

    // ---- conv1 aggregation: wave handles 32 nodes as 16 pairs; half-wave = node ----
    // 64 lanes read one full row per b128 (consecutive -> conflict-free)
    {
        const int hh = lane >> 5, c4 = lane & 31;
        float4 ga[16];
#pragma unroll
        for (int p = 0; p < 16; ++p) {
            int n = wv * 32 + 2 * p + hh;
            int ob = off[n], pcnt = off[n + 1] - ob;
            float4 a = *reinterpret_cast<const float4*>(&Hs[n][c4 * 4]);  // self (H0')
            for (int jc = 0; jc < pcnt; jc += 4) {
                unsigned idx4 = *reinterpret_cast<const unsigned*>(&srcs[ob + jc]);
                int s0 = idx4 & 255, s1 = (idx4 >> 8) & 255,
                    s2 = (idx4 >> 16) & 255, s3 = (idx4 >> 24);
                float4 v0 = *reinterpret_cast<const float4*>(&Hs[s0][c4 * 4]);
                float4 v1 = *reinterpret_cast<const float4*>(&Hs[s1][c4 * 4]);
                float4 v2 = *reinterpret_cast<const float4*>(&Hs[s2][c4 * 4]);
                float4 v3 = *reinterpret_cast<const float4*>(&Hs[s3][c4 * 4]);
                a.x += v0.x + v1.x + v2.x + v3.x;
                a.y += v0.y + v1.y + v2.y + v3.y;
                a.z += v0.z + v1.z + v2.z + v3.z;
                a.w += v0.w + v1.w + v2.w + v3.w;
            }
            ga[p] = a;
        }
        __syncthreads();   // all H0' reads done
        float4 b1v = *reinterpret_cast<const float4*>(&b1[c4 * 4]);
#pragma unroll
        for (int p = 0; p < 16; ++p) {
            int n = wv * 32 + 2 * p + hh;
            float r = rsl[n];
            float4 hv;
            hv.x = fmaxf(ga[p].x * r + b1v.x, 0.f);
            hv.y = fmaxf(ga[p].y * r + b1v.y, 0.f);
            hv.z = fmaxf(ga[p].z * r + b1v.z, 0.f);
            hv.w = fmaxf(ga[p].w * r + b1v.w, 0.f);
            *reinterpret_cast<float4*>(&Hs[n][c4 * 4]) = hv;
        }
    }
    __syncthreads();   // Hs = h (post-relu)

    // ---- spl = rs * (h @ Ws)  (staggered k to spread LDS banks) ----
    if (t < NPG) {
        float s = 0.f;
        for (int kk = 0; kk < 32; ++kk) {
            int k = (kk + t) & 31;
            float4 hv = *reinterpret_cast<const float4*>(&Hs[t][k * 4]);
            float4 wsv = *reinterpret_cast<const float4*>(&Ws[k * 4]);
            s += hv.x * wsv.x + hv.y * wsv.y + hv.z * wsv.z + hv.w * wsv.w;
        }
        spl[t] = rsl[t] * s;
        if (t == 0) spl[NPG] = 0.f;
    }
    __syncthreads();

    // ---- score = rs * (sum_e spl[s] + spl[self]) + bs ----
    if (t < NPG) {
        int ob = off[t], pcnt = off[t + 1] - ob;
        float sc = spl[t];
        for (int jc = 0; jc < pcnt; jc += 4) {
            unsigned idx4 = *reinterpret_cast<const unsigned*>(&srcs[ob + jc]);
            sc += spl[idx4 & 255] + spl[(idx4 >> 8) & 255]
                + spl[(idx4 >> 16) & 255] + spl[idx4 >> 24];
        }
        scl[t] = rsl[t] * sc + bsp[0];
    }
    __syncthreads();

    // ---- top-K by exact rank (stable: lower index wins ties) ----
    if (t < NPG) {
        float v = scl[t];
        int rank = 0;
        for (int j = 0; j < NPG; ++j) {
            float u = scl[j];
            rank += (u > v || (u == v && j < t)) ? 1 : 0;
        }
        wgt[t] = (rank < KSEL) ? tanhf(v) * (1.0f / KSEL) : 0.f;
    }
    __syncthreads();

    // ---- pooled[c] = sum_r wgt[r] * h[r][c]  (split rows over 2 halves) ----
    {
        int c = t & 127, hf = t >> 7;
        float s = 0.f;
        for (int r = hf * 64; r < hf * 64 + 64; ++r)
            s += wgt[r] * Hs[r][c];
        pp[t] = s;
    }
    __syncthreads();
    if (t < HID) pooled[t] = pp[t] + pp[t + 128];
    __syncthreads();

    // ---- out = pooled @ Wlin + blin  (split k over 2 halves) ----
    {
        int c = t & 127, hf = t >> 7;
        float s = 0.f;
        for (int k = hf * 64; k < hf * 64 + 64; ++k)
            s += pooled[k] * Wlin[k * HID + c];
        pp[t] = s;
    }
    __syncthreads();
    if (t < HID)
        out[(long)g * HID + t] = pp[t] + pp[t + 128] + blin[t];
}

extern "C" void kernel_launch(void* const* d_in, const int* in_sizes, int n_in,
                              void* d_out, int out_size, void* d_ws, size_t ws_size,
                              hipStream_t stream) {
    const float* x    = (const float*)d_in[0];
    const int*   ei   = (const int*)  d_in[1];
    const float* W1   = (const float*)d_in[3];
    const float* b1   = (const float*)d_in[4];
    const float* Ws   = (const float*)d_in[5];
    const float* bs   = (const float*)d_in[6];
    const float* Wlin = (const float*)d_in[7];
    const float* blin = (const float*)d_in[8];
    float* out = (float*)d_out;

    const int E = in_sizes[1] / 2;          // 1048576
    const int nnodes = in_sizes[0] / HID;   // 65536
    const int B = nnodes / NPG;             // 512
    const int epg = E / B;                  // 2048

    sagpool_fused<<<B, NT, 0, stream>>>(x, ei, ei + E, W1, b1, Ws, bs,
                                        Wlin, blin, out, epg);
}

// Round 3
// 121.423 us; speedup vs baseline: 1.7486x; 1.1497x over previous
//
#include <hip/hip_runtime.h>
#include <math.h>

#define NPG  128
#define HID  128
#define KSEL 64
#define NT   256
#define CSRCAP 2432   // 2048 edges + up to 128*3 pad (per-node counts padded to x4)

typedef __attribute__((ext_vector_type(8))) __bf16 bfrag;   // 8 bf16 = 4 VGPRs
typedef __attribute__((ext_vector_type(4))) float f4;

// Pre-kernel: split W1 (fp32 128x128) into bf16 hi/lo MFMA B-fragments in d_ws.
// Fragment (ks,ct): lane holds B[k=ks*32+quad*8+j][n=ct*16+(lane&15)], quad=lane>>4.
__global__ __launch_bounds__(64) void wsplit_kernel(const float* __restrict__ W1,
                                                    bfrag* __restrict__ whi,
                                                    bfrag* __restrict__ wlo)
{
    const int b = blockIdx.x;          // b = ks*8 + ct
    const int ks = b >> 3, ct = b & 7;
    const int lane = threadIdx.x;
    const int n = lane & 15, quad = lane >> 4;
    bfrag h, l;
#pragma unroll
    for (int j = 0; j < 8; ++j) {
        const int k = ks * 32 + quad * 8 + j;
        float w = W1[k * HID + ct * 16 + n];
        __bf16 hh = (__bf16)w;
        h[j] = hh;
        l[j] = (__bf16)(w - (float)hh);
    }
    whi[b * 64 + lane] = h;
    wlo[b * 64 + lane] = l;
}

__global__ __launch_bounds__(NT, 2) void sagpool_fused(
    const float* __restrict__ x,
    const int*   __restrict__ esrc,
    const int*   __restrict__ edst,
    const bfrag* __restrict__ whi,
    const bfrag* __restrict__ wlo,
    const float* __restrict__ b1,
    const float* __restrict__ Ws,
    const float* __restrict__ bsp,
    const float* __restrict__ Wlin,
    const float* __restrict__ blin,
    float* __restrict__ out,
    int epg)
{
    // ~74 KB LDS -> 2 blocks/CU
    __shared__ float Hs[NPG + 1][HID];          // H0' (rs-scaled) then h; row 128 = zero dummy
    __shared__ unsigned char srcs[CSRCAP];      // CSR src indices (uchar), pad entries = 128
    __shared__ int   degl[NPG];
    __shared__ int   off[NPG + 1];              // padded CSR offsets (multiples of 4)
    __shared__ int   cur[NPG];
    __shared__ float rsl[NPG];
    __shared__ float spl[NPG + 1];              // rs-scaled h@Ws; spl[128] = 0
    __shared__ float scl[NPG];
    __shared__ float wgt[NPG];
    __shared__ float pooled[HID];
    __shared__ float pp[2 * HID];
    __shared__ int   wsum[2];

    const int g = blockIdx.x, t = threadIdx.x;
    const int node0 = g * NPG;
    const long e0 = (long)g * epg;
    const int lane = t & 63, wv = t >> 6;

    // ---- load this graph's edges into registers (single global pass) ----
    int es[8], ed[8];
#pragma unroll
    for (int i = 0; i < 8; ++i) {
        int e = i * NT + t;
        es[i] = esrc[e0 + e] - node0;
        ed[i] = edst[e0 + e] - node0;
    }
    if (t < NPG) degl[t] = 0;
    if (t < HID) Hs[NPG][t] = 0.f;                       // dummy row for CSR padding
    for (int i = t; i < CSRCAP / 4; i += NT)
        reinterpret_cast<int*>(srcs)[i] = (int)0x80808080;  // fill with 128
    __syncthreads();

#pragma unroll
    for (int i = 0; i < 8; ++i) atomicAdd(&degl[ed[i]], 1);
    __syncthreads();

    // ---- rsqrt(deg+1) + exclusive scan of padded counts (wave shfl scan) ----
    int pc = 0;
    if (t < NPG) {
        int dg = degl[t];
        rsl[t] = rsqrtf((float)(dg + 1));
        pc = (dg + 3) & ~3;
    }
    int vscan = pc;
#pragma unroll
    for (int d = 1; d < 64; d <<= 1) {
        int u = __shfl_up(vscan, (unsigned)d, 64);
        if (lane >= d) vscan += u;
    }
    if (t < NPG && lane == 63) wsum[wv] = vscan;
    __syncthreads();
    if (t < NPG) {
        int inc = vscan + ((wv == 1) ? wsum[0] : 0);
        int ex = inc - pc;
        off[t] = ex; cur[t] = ex;
        if (t == NPG - 1) off[NPG] = inc;
    }
    __syncthreads();

    // ---- scatter edges into CSR (uchar local src idx) ----
#pragma unroll
    for (int i = 0; i < 8; ++i) {
        int slot = atomicAdd(&cur[ed[i]], 1);
        srcs[slot] = (unsigned char)es[i];
    }

    // ---- GEMM1 via MFMA: H0 = (xh+xl) @ (wh+wl), 4 bf16 products, fp32 accum ----
    // wave wv -> output rows [wv*32, wv*32+32) x all 128 cols = 2x8 tiles of 16x16
    {
        const int mrow = lane & 15, quad = lane >> 4;
        f4 acc[2][8];
#pragma unroll
        for (int rt = 0; rt < 2; ++rt)
#pragma unroll
            for (int ct = 0; ct < 8; ++ct) {
                acc[rt][ct].x = 0.f; acc[rt][ct].y = 0.f;
                acc[rt][ct].z = 0.f; acc[rt][ct].w = 0.f;
            }

        const float* xw = x + (long)(node0 + wv * 32) * HID;
#pragma unroll
        for (int ks = 0; ks < 4; ++ks) {
            bfrag ah[2], al[2];
#pragma unroll
            for (int rt = 0; rt < 2; ++rt) {
                const float* xr = xw + (rt * 16 + mrow) * HID + ks * 32 + quad * 8;
                float4 v0 = *reinterpret_cast<const float4*>(xr);
                float4 v1 = *reinterpret_cast<const float4*>(xr + 4);
                float xv[8] = {v0.x, v0.y, v0.z, v0.w, v1.x, v1.y, v1.z, v1.w};
#pragma unroll
                for (int j = 0; j < 8; ++j) {
                    __bf16 hh = (__bf16)xv[j];
                    ah[rt][j] = hh;
                    al[rt][j] = (__bf16)(xv[j] - (float)hh);
                }
            }
#pragma unroll
            for (int ct = 0; ct < 8; ++ct) {
                bfrag bh = whi[(ks * 8 + ct) * 64 + lane];
                bfrag bl = wlo[(ks * 8 + ct) * 64 + lane];
#pragma unroll
                for (int rt = 0; rt < 2; ++rt) {
                    acc[rt][ct] = __builtin_amdgcn_mfma_f32_16x16x32_bf16(ah[rt], bh, acc[rt][ct], 0, 0, 0);
                    acc[rt][ct] = __builtin_amdgcn_mfma_f32_16x16x32_bf16(al[rt], bh, acc[rt][ct], 0, 0, 0);
                    acc[rt][ct] = __builtin_amdgcn_mfma_f32_16x16x32_bf16(ah[rt], bl, acc[rt][ct], 0, 0, 0);
                    acc[rt][ct] = __builtin_amdgcn_mfma_f32_16x16x32_bf16(al[rt], bl, acc[rt][ct], 0, 0, 0);
                }
            }
        }
        // epilogue: scale rows by rs (rsl ready: synced above), write H0' to LDS
        // C/D layout: col = ct*16 + (lane&15), row = rt*16 + quad*4 + reg
#pragma unroll
        for (int rt = 0; rt < 2; ++rt)
#pragma unroll
            for (int reg = 0; reg < 4; ++reg) {
                const int m = wv * 32 + rt * 16 + quad * 4 + reg;
                const float rs = rsl[m];
#pragma unroll
                for (int ct = 0; ct < 8; ++ct)
                    Hs[m][ct * 16 + mrow] = acc[rt][ct][reg] * rs;
            }
    }
    __syncthreads();   // H0' complete, CSR complete

    // ---- conv1 aggregation: wave handles 32 nodes as 16 pairs; half-wave = node ----
    {
        const int hh = lane >> 5, c4 = lane & 31;
        float4 ga[16];
#pragma unroll
        for (int p = 0; p < 16; ++p) {
            int n = wv * 32 + 2 * p + hh;
            int ob = off[n], pcnt = off[n + 1] - ob;
            float4 a = *reinterpret_cast<const float4*>(&Hs[n][c4 * 4]);  // self (H0')
            for (int jc = 0; jc < pcnt; jc += 4) {
                unsigned idx4 = *reinterpret_cast<const unsigned*>(&srcs[ob + jc]);
                int s0 = idx4 & 255, s1 = (idx4 >> 8) & 255,
                    s2 = (idx4 >> 16) & 255, s3 = (idx4 >> 24);
                float4 v0 = *reinterpret_cast<const float4*>(&Hs[s0][c4 * 4]);
                float4 v1 = *reinterpret_cast<const float4*>(&Hs[s1][c4 * 4]);
                float4 v2 = *reinterpret_cast<const float4*>(&Hs[s2][c4 * 4]);
                float4 v3 = *reinterpret_cast<const float4*>(&Hs[s3][c4 * 4]);
                a.x += v0.x + v1.x + v2.x + v3.x;
                a.y += v0.y + v1.y + v2.y + v3.y;
                a.z += v0.z + v1.z + v2.z + v3.z;
                a.w += v0.w + v1.w + v2.w + v3.w;
            }
            ga[p] = a;
        }
        __syncthreads();   // all H0' reads done
        float4 b1v = *reinterpret_cast<const float4*>(&b1[c4 * 4]);
#pragma unroll
        for (int p = 0; p < 16; ++p) {
            int n = wv * 32 + 2 * p + hh;
            float r = rsl[n];
            float4 hv;
            hv.x = fmaxf(ga[p].x * r + b1v.x, 0.f);
            hv.y = fmaxf(ga[p].y * r + b1v.y, 0.f);
            hv.z = fmaxf(ga[p].z * r + b1v.z, 0.f);
            hv.w = fmaxf(ga[p].w * r + b1v.w, 0.f);
            *reinterpret_cast<float4*>(&Hs[n][c4 * 4]) = hv;
        }
    }
    __syncthreads();   // Hs = h (post-relu)

    // ---- spl = rs * (h @ Ws)  (staggered k to spread LDS banks) ----
    if (t < NPG) {
        float s = 0.f;
        for (int kk = 0; kk < 32; ++kk) {
            int k = (kk + t) & 31;
            float4 hv = *reinterpret_cast<const float4*>(&Hs[t][k * 4]);
            float4 wsv = *reinterpret_cast<const float4*>(&Ws[k * 4]);
            s += hv.x * wsv.x + hv.y * wsv.y + hv.z * wsv.z + hv.w * wsv.w;
        }
        spl[t] = rsl[t] * s;
        if (t == 0) spl[NPG] = 0.f;
    }
    __syncthreads();

    // ---- score = rs * (sum_e spl[s] + spl[self]) + bs ----
    if (t < NPG) {
        int ob = off[t], pcnt = off[t + 1] - ob;
        float sc = spl[t];
        for (int jc = 0; jc < pcnt; jc += 4) {
            unsigned idx4 = *reinterpret_cast<const unsigned*>(&srcs[ob + jc]);
            sc += spl[idx4 & 255] + spl[(idx4 >> 8) & 255]
                + spl[(idx4 >> 16) & 255] + spl[idx4 >> 24];
        }
        scl[t] = rsl[t] * sc + bsp[0];
    }
    __syncthreads();

    // ---- top-K by exact rank (stable: lower index wins ties) ----
    if (t < NPG) {
        float v = scl[t];
        int rank = 0;
        for (int j = 0; j < NPG; ++j) {
            float u = scl[j];
            rank += (u > v || (u == v && j < t)) ? 1 : 0;
        }
        wgt[t] = (rank < KSEL) ? tanhf(v) * (1.0f / KSEL) : 0.f;
    }
    __syncthreads();

    // ---- pooled[c] = sum_r wgt[r] * h[r][c]  (split rows over 2 halves) ----
    {
        int c = t & 127, hf = t >> 7;
        float s = 0.f;
        for (int r = hf * 64; r < hf * 64 + 64; ++r)
            s += wgt[r] * Hs[r][c];
        pp[t] = s;
    }
    __syncthreads();
    if (t < HID) pooled[t] = pp[t] + pp[t + 128];
    __syncthreads();

    // ---- out = pooled @ Wlin + blin  (split k over 2 halves) ----
    {
        int c = t & 127, hf = t >> 7;
        float s = 0.f;
        for (int k = hf * 64; k < hf * 64 + 64; ++k)
            s += pooled[k] * Wlin[k * HID + c];
        pp[t] = s;
    }
    __syncthreads();
    if (t < HID)
        out[(long)g * HID + t] = pp[t] + pp[t + 128] + blin[t];
}

extern "C" void kernel_launch(void* const* d_in, const int* in_sizes, int n_in,
                              void* d_out, int out_size, void* d_ws, size_t ws_size,
                              hipStream_t stream) {
    const float* x    = (const float*)d_in[0];
    const int*   ei   = (const int*)  d_in[1];
    const float* W1   = (const float*)d_in[3];
    const float* b1   = (const float*)d_in[4];
    const float* Ws   = (const float*)d_in[5];
    const float* bs   = (const float*)d_in[6];
    const float* Wlin = (const float*)d_in[7];
    const float* blin = (const float*)d_in[8];
    float* out = (float*)d_out;

    const int E = in_sizes[1] / 2;          // 1048576
    const int nnodes = in_sizes[0] / HID;   // 65536
    const int B = nnodes / NPG;             // 512
    const int epg = E / B;                  // 2048

    bfrag* whi = reinterpret_cast<bfrag*>(d_ws);       // 32 KB hi frags
    bfrag* wlo = whi + 32 * 64;                        // 32 KB lo frags

    wsplit_kernel<<<32, 64, 0, stream>>>(W1, whi, wlo);
    sagpool_fused<<<B, NT, 0, stream>>>(x, ei, ei + E, whi, wlo, b1, Ws, bs,
                                        Wlin, blin, out, epg);
}

// Round 4
// 111.777 us; speedup vs baseline: 1.8995x; 1.0863x over previous
//
#include <hip/hip_runtime.h>
#include <math.h>

#define NPG  128
#define HID  128
#define KSEL 64
#define NT   256
#define HS   132   // HpT row stride in dwords (16B-aligned runs, uniform bank groups)
#define AS   17    // AdjN row stride in dwords (odd -> spread banks)

typedef __attribute__((ext_vector_type(8))) __bf16 bfrag;   // 8 bf16 = 4 VGPRs
typedef __attribute__((ext_vector_type(4))) float f4;

static __device__ __forceinline__ __bf16 us2bf(unsigned short u) {
    union { unsigned short s; __bf16 b; } x; x.s = u; return x.b;
}
static __device__ __forceinline__ unsigned short bf2us(__bf16 b) {
    union { unsigned short s; __bf16 b; } x; x.b = b; return x.s;
}

// Pre-kernel: split W1 (fp32 128x128) into bf16 hi/lo MFMA B-fragments in d_ws.
// Fragment (ks,ct): lane holds B[k=ks*32+quad*8+j][n=ct*16+(lane&15)], quad=lane>>4.
__global__ __launch_bounds__(64) void wsplit_kernel(const float* __restrict__ W1,
                                                    bfrag* __restrict__ whi,
                                                    bfrag* __restrict__ wlo)
{
    const int b = blockIdx.x;          // b = ks*8 + ct
    const int ks = b >> 3, ct = b & 7;
    const int lane = threadIdx.x;
    const int n = lane & 15, quad = lane >> 4;
    bfrag h, l;
#pragma unroll
    for (int j = 0; j < 8; ++j) {
        const int k = ks * 32 + quad * 8 + j;
        float w = W1[k * HID + ct * 16 + n];
        __bf16 hh = (__bf16)w;
        h[j] = hh;
        l[j] = (__bf16)(w - (float)hh);
    }
    whi[b * 64 + lane] = h;
    wlo[b * 64 + lane] = l;
}

__global__ __launch_bounds__(NT, 2) void sagpool_fused(
    const float* __restrict__ x,
    const int*   __restrict__ esrc,
    const int*   __restrict__ edst,
    const bfrag* __restrict__ whi,
    const bfrag* __restrict__ wlo,
    const float* __restrict__ b1,
    const float* __restrict__ Ws,
    const float* __restrict__ bsp,
    const float* __restrict__ Wlin,
    const float* __restrict__ blin,
    float* __restrict__ out,
    int epg)
{
    // ~79 KB LDS -> 2 blocks/CU
    __shared__ __align__(16) unsigned HpT[HID * HS];   // H0' hi|lo packed, [feat][node]
    __shared__ __align__(16) unsigned AdjN[NPG * AS];  // nibble counts of Adj+I, [dst][src]
    __shared__ __align__(16) float rsl[NPG];
    __shared__ __align__(16) float spl[NPG];
    __shared__ __align__(16) float scl[NPG];           // scores; reused as pooled
    __shared__ __align__(16) float wgt[NPG];
    __shared__ __align__(16) float pp[4 * HID];

    const int g = blockIdx.x, t = threadIdx.x;
    const int node0 = g * NPG;
    const long e0 = (long)g * epg;
    const int lane = t & 63, wv = t >> 6;
    const int n16 = lane & 15, quad = lane >> 4;

    // ---- early global loads (edges, x A-frag rows, small vectors) ----
    int es[8], ed[8];
#pragma unroll
    for (int i = 0; i < 8; ++i) {
        int e = i * NT + t;
        es[i] = esrc[e0 + e] - node0;
        ed[i] = edst[e0 + e] - node0;
    }
    float4 xv[16];
    {
        const float* xw = x + (long)(node0 + wv * 32) * HID;
#pragma unroll
        for (int rt = 0; rt < 2; ++rt)
#pragma unroll
            for (int ks = 0; ks < 4; ++ks) {
                const float* xr = xw + (rt * 16 + n16) * HID + ks * 32 + quad * 8;
                xv[(rt * 4 + ks) * 2]     = *reinterpret_cast<const float4*>(xr);
                xv[(rt * 4 + ks) * 2 + 1] = *reinterpret_cast<const float4*>(xr + 4);
            }
    }
    float b1v[8], wsv[8];
#pragma unroll
    for (int ct = 0; ct < 8; ++ct) {
        b1v[ct] = b1[ct * 16 + n16];
        wsv[ct] = Ws[ct * 16 + n16];
    }
    const float bsv = bsp[0];

    // ---- build Adj+I as nibble counts ----
    for (int i = t; i < NPG * AS; i += NT) AdjN[i] = 0u;
    __syncthreads();
#pragma unroll
    for (int i = 0; i < 8; ++i)
        atomicAdd(&AdjN[ed[i] * AS + (es[i] >> 3)], 1u << ((es[i] & 7) * 4));
    __syncthreads();

    // diagonal +1, then deg+1 = nibble row-sum -> rsqrt
    if (t < NPG) {
        unsigned* row = &AdjN[t * AS];
        row[t >> 3] += 1u << ((t & 7) * 4);
        unsigned sum = 0;
#pragma unroll
        for (int w = 0; w < 16; ++w) {
            unsigned u = row[w];
            unsigned b = (u & 0x0F0F0F0Fu) + ((u >> 4) & 0x0F0F0F0Fu);
            sum += (b * 0x01010101u) >> 24;
        }
        rsl[t] = rsqrtf((float)sum);
    }
    __syncthreads();

    // ---- GEMM1 via MFMA: H0 = (xh+xl)@(wh+wl), rows [wv*32, wv*32+32) ----
    bfrag ah[8], al[8];
#pragma unroll
    for (int r = 0; r < 8; ++r) {
        float4 a = xv[2 * r], b = xv[2 * r + 1];
        float vv[8] = {a.x, a.y, a.z, a.w, b.x, b.y, b.z, b.w};
#pragma unroll
        for (int j = 0; j < 8; ++j) {
            __bf16 hb = (__bf16)vv[j];
            ah[r][j] = hb;
            al[r][j] = (__bf16)(vv[j] - (float)hb);
        }
    }
    f4 acc[2][8];
#pragma unroll
    for (int rt = 0; rt < 2; ++rt)
#pragma unroll
        for (int ct = 0; ct < 8; ++ct) {
            acc[rt][ct].x = 0.f; acc[rt][ct].y = 0.f;
            acc[rt][ct].z = 0.f; acc[rt][ct].w = 0.f;
        }
#pragma unroll
    for (int ks = 0; ks < 4; ++ks)
#pragma unroll
        for (int ct = 0; ct < 8; ++ct) {
            bfrag bh = whi[(ks * 8 + ct) * 64 + lane];
            bfrag bl = wlo[(ks * 8 + ct) * 64 + lane];
#pragma unroll
            for (int rt = 0; rt < 2; ++rt) {
                const int r = rt * 4 + ks;
                acc[rt][ct] = __builtin_amdgcn_mfma_f32_16x16x32_bf16(ah[r], bh, acc[rt][ct], 0, 0, 0);
                acc[rt][ct] = __builtin_amdgcn_mfma_f32_16x16x32_bf16(al[r], bh, acc[rt][ct], 0, 0, 0);
                acc[rt][ct] = __builtin_amdgcn_mfma_f32_16x16x32_bf16(ah[r], bl, acc[rt][ct], 0, 0, 0);
                acc[rt][ct] = __builtin_amdgcn_mfma_f32_16x16x32_bf16(al[r], bl, acc[rt][ct], 0, 0, 0);
            }
        }

    // epilogue: H0' = rs*H0, pack hi|lo dword, b128 stores feature-major
#pragma unroll
    for (int rt = 0; rt < 2; ++rt) {
        const int mb = wv * 32 + rt * 16 + quad * 4;
        f4 rs4 = *reinterpret_cast<const f4*>(&rsl[mb]);
#pragma unroll
        for (int ct = 0; ct < 8; ++ct) {
            uint4 st;
            unsigned pw[4];
#pragma unroll
            for (int reg = 0; reg < 4; ++reg) {
                float v = acc[rt][ct][reg] * rs4[reg];
                __bf16 hb = (__bf16)v;
                __bf16 lb = (__bf16)(v - (float)hb);
                pw[reg] = ((unsigned)bf2us(hb) << 16) | (unsigned)bf2us(lb);
            }
            st.x = pw[0]; st.y = pw[1]; st.z = pw[2]; st.w = pw[3];
            *reinterpret_cast<uint4*>(&HpT[(ct * 16 + n16) * HS + mb]) = st;
        }
    }
    __syncthreads();

    // ---- conv1 aggregation via MFMA: agg = (Adj+I) @ H0'(hi+lo) ----
    f4 hacc[2][8];
#pragma unroll
    for (int mt = 0; mt < 2; ++mt)
#pragma unroll
        for (int ct = 0; ct < 8; ++ct) {
            hacc[mt][ct].x = 0.f; hacc[mt][ct].y = 0.f;
            hacc[mt][ct].z = 0.f; hacc[mt][ct].w = 0.f;
        }
#pragma unroll
    for (int ks = 0; ks < 4; ++ks) {
        bfrag af[2];
#pragma unroll
        for (int mt = 0; mt < 2; ++mt) {
            unsigned w = AdjN[(wv * 32 + mt * 16 + n16) * AS + ks * 4 + quad];
#pragma unroll
            for (int j = 0; j < 8; ++j)
                af[mt][j] = (__bf16)(float)((w >> (4 * j)) & 15u);
        }
#pragma unroll
        for (int ct = 0; ct < 8; ++ct) {
            const unsigned* bp = &HpT[(ct * 16 + n16) * HS + ks * 32 + quad * 8];
            uint4 w0 = *reinterpret_cast<const uint4*>(bp);
            uint4 w1 = *reinterpret_cast<const uint4*>(bp + 4);
            unsigned ww[8] = {w0.x, w0.y, w0.z, w0.w, w1.x, w1.y, w1.z, w1.w};
            bfrag bh, bl;
#pragma unroll
            for (int j = 0; j < 8; ++j) {
                bh[j] = us2bf((unsigned short)(ww[j] >> 16));
                bl[j] = us2bf((unsigned short)(ww[j] & 0xFFFFu));
            }
#pragma unroll
            for (int mt = 0; mt < 2; ++mt) {
                hacc[mt][ct] = __builtin_amdgcn_mfma_f32_16x16x32_bf16(af[mt], bh, hacc[mt][ct], 0, 0, 0);
                hacc[mt][ct] = __builtin_amdgcn_mfma_f32_16x16x32_bf16(af[mt], bl, hacc[mt][ct], 0, 0, 0);
            }
        }
    }

    // epilogue in regs: h = relu(rs*agg + b1)   (h stays in registers!)
    f4 rsm[2];
#pragma unroll
    for (int mt = 0; mt < 2; ++mt)
        rsm[mt] = *reinterpret_cast<const f4*>(&rsl[wv * 32 + mt * 16 + quad * 4]);
#pragma unroll
    for (int mt = 0; mt < 2; ++mt)
#pragma unroll
        for (int ct = 0; ct < 8; ++ct)
#pragma unroll
            for (int reg = 0; reg < 4; ++reg)
                hacc[mt][ct][reg] = fmaxf(hacc[mt][ct][reg] * rsm[mt][reg] + b1v[ct], 0.f);

    // ---- spl' = rs * (h @ Ws): per-row dot, shfl_xor reduce over n-group ----
    {
        float dot[2][4];
#pragma unroll
        for (int mt = 0; mt < 2; ++mt)
#pragma unroll
            for (int reg = 0; reg < 4; ++reg) dot[mt][reg] = 0.f;
#pragma unroll
        for (int ct = 0; ct < 8; ++ct)
#pragma unroll
            for (int mt = 0; mt < 2; ++mt)
#pragma unroll
                for (int reg = 0; reg < 4; ++reg)
                    dot[mt][reg] += hacc[mt][ct][reg] * wsv[ct];
#pragma unroll
        for (int d = 1; d < 16; d <<= 1)
#pragma unroll
            for (int mt = 0; mt < 2; ++mt)
#pragma unroll
                for (int reg = 0; reg < 4; ++reg)
                    dot[mt][reg] += __shfl_xor(dot[mt][reg], d, 64);
        if (n16 == 0) {
#pragma unroll
            for (int mt = 0; mt < 2; ++mt)
#pragma unroll
                for (int reg = 0; reg < 4; ++reg)
                    spl[wv * 32 + mt * 16 + quad * 4 + reg] = rsm[mt][reg] * dot[mt][reg];
        }
    }
    __syncthreads();

    // ---- score = rs * ((Adj+I) @ spl') + bs  via dense nibble rows ----
    if (t < NPG) {
        const unsigned* row = &AdjN[t * AS];
        float sc = 0.f;
#pragma unroll
        for (int w = 0; w < 16; ++w) {
            unsigned u = row[w];
            const float* sp = &spl[w * 8];
            sc += (float)(u & 15u)         * sp[0] + (float)((u >> 4)  & 15u) * sp[1]
                + (float)((u >> 8)  & 15u) * sp[2] + (float)((u >> 12) & 15u) * sp[3]
                + (float)((u >> 16) & 15u) * sp[4] + (float)((u >> 20) & 15u) * sp[5]
                + (float)((u >> 24) & 15u) * sp[6] + (float)(u >> 28)         * sp[7];
        }
        scl[t] = rsl[t] * sc + bsv;
    }
    __syncthreads();

    // ---- top-K by exact rank (stable: lower index wins ties) ----
    if (t < NPG) {
        float v = scl[t];
        int rank = 0;
        for (int j = 0; j < NPG; ++j) {
            float u = scl[j];
            rank += (u > v || (u == v && j < t)) ? 1 : 0;
        }
        wgt[t] = (rank < KSEL) ? tanhf(v) * (1.0f / KSEL) : 0.f;
    }
    __syncthreads();

    // ---- pooled[c] = sum_m wgt[m]*h[m][c] from registers; shfl over quads ----
    {
        float p[8];
        f4 wm[2];
#pragma unroll
        for (int mt = 0; mt < 2; ++mt)
            wm[mt] = *reinterpret_cast<const f4*>(&wgt[wv * 32 + mt * 16 + quad * 4]);
#pragma unroll
        for (int ct = 0; ct < 8; ++ct) {
            float s = 0.f;
#pragma unroll
            for (int mt = 0; mt < 2; ++mt)
#pragma unroll
                for (int reg = 0; reg < 4; ++reg)
                    s += wm[mt][reg] * hacc[mt][ct][reg];
            p[ct] = s;
        }
#pragma unroll
        for (int d = 16; d < 64; d <<= 1)
#pragma unroll
            for (int ct = 0; ct < 8; ++ct)
                p[ct] += __shfl_xor(p[ct], d, 64);
        if (quad == 0) {
#pragma unroll
            for (int ct = 0; ct < 8; ++ct)
                pp[wv * HID + ct * 16 + n16] = p[ct];
        }
    }
    __syncthreads();
    if (t < NPG)
        scl[t] = pp[t] + pp[HID + t] + pp[2 * HID + t] + pp[3 * HID + t];  // pooled
    __syncthreads();

    // ---- out = pooled @ Wlin + blin (split-k over 2 halves) ----
    {
        const int c = t & 127, hf = t >> 7;
        float s = 0.f;
        for (int k = hf * 64; k < hf * 64 + 64; ++k)
            s += scl[k] * Wlin[k * HID + c];
        pp[t] = s;
    }
    __syncthreads();
    if (t < NPG)
        out[(long)g * HID + t] = pp[t] + pp[t + 128] + blin[t];
}

extern "C" void kernel_launch(void* const* d_in, const int* in_sizes, int n_in,
                              void* d_out, int out_size, void* d_ws, size_t ws_size,
                              hipStream_t stream) {
    const float* x    = (const float*)d_in[0];
    const int*   ei   = (const int*)  d_in[1];
    const float* W1   = (const float*)d_in[3];
    const float* b1   = (const float*)d_in[4];
    const float* Ws   = (const float*)d_in[5];
    const float* bs   = (const float*)d_in[6];
    const float* Wlin = (const float*)d_in[7];
    const float* blin = (const float*)d_in[8];
    float* out = (float*)d_out;

    const int E = in_sizes[1] / 2;          // 1048576
    const int nnodes = in_sizes[0] / HID;   // 65536
    const int B = nnodes / NPG;             // 512
    const int epg = E / B;                  // 2048

    bfrag* whi = reinterpret_cast<bfrag*>(d_ws);       // 32 KB hi frags
    bfrag* wlo = whi + 32 * 64;                        // 32 KB lo frags

    wsplit_kernel<<<32, 64, 0, stream>>>(W1, whi, wlo);
    sagpool_fused<<<B, NT, 0, stream>>>(x, ei, ei + E, whi, wlo, b1, Ws, bs,
                                        Wlin, blin, out, epg);
}